// Round 11
// baseline (810.195 us; speedup 1.0000x reference)
//
#include <hip/hip_runtime.h>
#include <hip/hip_bf16.h>
#include <hip/hip_fp16.h>
#include <math.h>

#define NN 65536
#define NE 1048576
#define NB 64
#define HD 128
#define NL 3

// ---- workspace layout (float offsets) ----
#define O_CSUM   0
#define O_CCNT   192
#define O_LCNT   256
#define O_GSUM   320         // -> 8512
#define O_DEGI   8512        // -> 74048
#define O_POSREL 74048       // -> 270656
#define O_RC     270656      // (unused now) -> 1319232
#define O_XHI    1319232     // NN*128 ushort -> 5513536
#define O_XLO    5513536     // -> 9707840
#define O_P      9707840     // NN*128 fp16 -> 13902144 used; region to 18096448
#define O_RCD    13902144    // uint2[NE] (rc, dist) -> 15999296 (O_P slack)
#define O_Q      18096448    // NN*128 fp16 -> 22290752 used; region to 26485056
#define O_C1H    22290752    // fp16 [3][128] dist-col of W1 -> 22290944
#define O_EW     22291456    // fp32 [100][128] emb@W + b -> 22304256 (Q-region slack)
#define O_MSUM   26485056    // -> 34873664
#define O_W2T    34873664    // 3*128*128 fp16 (SWIZZLED layout) -> 34898240
#define O_W1TH   34898240    // -> 34947392   (packed [l][kb16][c256][8])
#define O_W1TL   34947392    // -> 34996544
#define O_WUTH   34996544    // -> 35045696   (packed [l][kb32][c128][8])
#define O_WUTL   35045696    // -> 35094848
#define O_CHK    35094848    // 256 ints -> 35095104 (~140.4 MB)

typedef __attribute__((ext_vector_type(8))) short bf16x8;
typedef __attribute__((ext_vector_type(8))) _Float16 f16x8;
typedef __attribute__((ext_vector_type(8))) unsigned short u16x8;
typedef __attribute__((ext_vector_type(4))) float f32x4;

__device__ __forceinline__ void atomAdd(float* p, float v) { unsafeAtomicAdd(p, v); }

__device__ __forceinline__ unsigned short f2bf(float f) {
    union { __hip_bfloat16 h; unsigned short u; } cv;
    cv.h = __float2bfloat16(f);
    return cv.u;
}
__device__ __forceinline__ float bf2f(unsigned short u) {
    union { float f; unsigned v; } c; c.v = ((unsigned)u) << 16; return c.f;
}
__device__ __forceinline__ void split2(float v, unsigned short& h, unsigned short& l) {
    h = f2bf(v); l = f2bf(v - bf2f(h));
}
__device__ __forceinline__ unsigned short f2h(float f) {
    union { __half h; unsigned short u; } c; c.h = __float2half(f); return c.u;
}

// ---------------- stats ----------------
__global__ __launch_bounds__(256) void stats_kernel(
    const float* __restrict__ pos, const int* __restrict__ batch,
    const int* __restrict__ ntype,
    float* __restrict__ csum, float* __restrict__ ccnt, float* __restrict__ lcnt)
{
    __shared__ float s[NB * 5];
    const int tid = threadIdx.x;
    for (int i = tid; i < NB * 5; i += 256) s[i] = 0.f;
    __syncthreads();
    const int n = blockIdx.x * 256 + tid;
    const int b = batch[n];
    atomicAdd(&s[b*5+0], pos[n*3+0]);
    atomicAdd(&s[b*5+1], pos[n*3+1]);
    atomicAdd(&s[b*5+2], pos[n*3+2]);
    atomicAdd(&s[b*5+3], 1.f);
    if (ntype[n] == 1) atomicAdd(&s[b*5+4], 1.f);
    __syncthreads();
    for (int i = tid; i < NB * 5; i += 256) {
        float v = s[i];
        if (v != 0.f) {
            int b2 = i / 5, f = i - b2*5;
            if (f < 3)       atomAdd(&csum[b2*3+f], v);
            else if (f == 3) atomAdd(&ccnt[b2], v);
            else             atomAdd(&lcnt[b2], v);
        }
    }
}

// ---------------- degree histogram ----------------
__global__ __launch_bounds__(256) void deg_kernel(const int* __restrict__ row, int* __restrict__ degi)
{
    const int e = blockIdx.x * 256 + threadIdx.x;
    atomicAdd(&degi[row[e]], 1);
}

// ---------------- two-level scan ----------------
__global__ __launch_bounds__(256) void scanA_kernel(const int* __restrict__ degi, int* __restrict__ chunkSum)
{
    __shared__ int red[4];
    const int t = threadIdx.x, b = blockIdx.x;
    int v = degi[b*256 + t];
    #pragma unroll
    for (int off = 32; off > 0; off >>= 1) v += __shfl_down(v, off, 64);
    if ((t & 63) == 0) red[t >> 6] = v;
    __syncthreads();
    if (t == 0) chunkSum[b] = red[0] + red[1] + red[2] + red[3];
}

__global__ __launch_bounds__(256) void scanB_kernel(int* __restrict__ chunkSum)
{
    __shared__ int s[256];
    const int t = threadIdx.x;
    const int v = chunkSum[t];
    s[t] = v;
    __syncthreads();
    #pragma unroll
    for (int off = 1; off < 256; off <<= 1) {
        int u = (t >= off) ? s[t - off] : 0;
        __syncthreads();
        s[t] += u;
        __syncthreads();
    }
    chunkSum[t] = s[t] - v;   // exclusive
}

__global__ __launch_bounds__(256) void scanC_kernel(const int* __restrict__ degi,
                                                    const int* __restrict__ chunkOff,
                                                    int* __restrict__ rowStart)
{
    __shared__ int s[256];
    const int t = threadIdx.x, b = blockIdx.x;
    const int v = degi[b*256 + t];
    s[t] = v;
    __syncthreads();
    #pragma unroll
    for (int off = 1; off < 256; off <<= 1) {
        int u = (t >= off) ? s[t - off] : 0;
        __syncthreads();
        s[t] += u;
        __syncthreads();
    }
    rowStart[b*256 + t] = chunkOff[b] + s[t] - v;
}

// ---------------- counting-sort scatter: single 8B store per edge (rc + dist) --------
__global__ __launch_bounds__(256) void scatter_kernel(
    const int* __restrict__ row, const int* __restrict__ col,
    const int* __restrict__ rowStart, int* __restrict__ cnt,
    uint2* __restrict__ rcD,
    const float* __restrict__ posrel)
{
    const int e = blockIdx.x * 256 + threadIdx.x;
    const int r = row[e], c = col[e];
    const float dx = posrel[c*3+0] - posrel[r*3+0];
    const float dy = posrel[c*3+1] - posrel[r*3+1];
    const float dz = posrel[c*3+2] - posrel[r*3+2];
    const float dist = sqrtf(dx*dx + dy*dy + dz*dz);
    const int p = rowStart[r] + atomicAdd(&cnt[r], 1);
    rcD[p] = make_uint2(((unsigned)r << 16) | (unsigned)c, __float_as_uint(dist));
}

// ---------------- pos_rel ----------------
__global__ __launch_bounds__(256) void posrel_kernel(
    const float* __restrict__ pos, const int* __restrict__ batch,
    const float* __restrict__ csum, const float* __restrict__ ccnt,
    float* __restrict__ posrel)
{
    const int n = blockIdx.x * 256 + threadIdx.x;
    const int b = batch[n];
    const float inv = 1.f / fmaxf(ccnt[b], 1.f);
    posrel[n*3+0] = pos[n*3+0] - csum[b*3+0]*inv;
    posrel[n*3+1] = pos[n*3+1] - csum[b*3+1]*inv;
    posrel[n*3+2] = pos[n*3+2] - csum[b*3+2]*inv;
}

// ---------------- weight prep: packed split-bf16 ([kb][c][8]) + W2T swz + c1h + EW ----
__global__ __launch_bounds__(256) void wprep_kernel(
    const float* __restrict__ mw1, const float* __restrict__ uw,
    const float* __restrict__ mw2,
    const float* __restrict__ lin_w, const float* __restrict__ lin_b,
    const float* __restrict__ emb,
    unsigned short* __restrict__ w1th, unsigned short* __restrict__ w1tl,
    unsigned short* __restrict__ wuth, unsigned short* __restrict__ wutl,
    unsigned short* __restrict__ w2t, unsigned short* __restrict__ c1h,
    float* __restrict__ EW)
{
    const int idx = blockIdx.x * 256 + threadIdx.x;   // 98304
    {   // W1T packed: [l][kb 0..15][c 0..255][w 0..7]; element = W1T[l][c][kb*8+w]
        const int l = idx >> 15, rem = idx & 32767;
        const int w = rem & 7, t = rem >> 3;
        const int c = t & 255, kb = t >> 8;
        const int k = kb*8 + w;
        const int kk = (c < 128) ? k : (128 + k);
        const int cc = c & 127;
        const float v = mw1[l*257*128 + kk*128 + cc];
        unsigned short h, lo; split2(v, h, lo);
        w1th[idx] = h; w1tl[idx] = lo;
    }
    {   // WuT packed: [l][kb 0..31][c 0..127][w 0..7]; element = uw[l][kb*8+w][c]
        const int l = idx >> 15, rem = idx & 32767;
        const int w = rem & 7, t = rem >> 3;
        const int c = t & 127, kb = t >> 7;
        const int k = kb*8 + w;
        const float v = uw[l*256*128 + k*128 + c];
        unsigned short h, lo; split2(v, h, lo);
        wuth[idx] = h; wutl[idx] = lo;
    }
    if (idx < 49152) {
        // W2T fp16, XOR-swizzled 16B blocks: position blk=(n*16+cs) holds logical
        // (n, c = cs ^ (n&7)) so LDS ds_read_b128 at n*16 + (c^(n&7)) is conflict-free.
        const int l = idx >> 14, rem = idx & 16383;
        const int blk = rem >> 3, win = rem & 7;
        const int n = blk >> 4, cs = blk & 15;
        const int c = cs ^ (n & 7);
        const int k = c*8 + win;
        w2t[idx] = f2h(mw2[(l << 14) + k*128 + n]);
    }
    if (idx < 384) {     // c1h fp16: dist column (row 256) of W1, [l][c]
        const int l = idx >> 7, c = idx & 127;
        c1h[idx] = f2h(mw1[l*257*128 + 256*128 + c]);
    }
    if (idx < 12800) {   // EW = emb(100x128) @ lin_w[:128] + lin_b   (exact fp32)
        const int j = idx & 127, zz = idx >> 7;
        float acc = lin_b[j];
        for (int k = 0; k < 128; ++k)
            acc += emb[zz*128 + k] * lin_w[k*128 + j];
        EW[idx] = acc;
    }
}

// ---------------- lin_in: gather EW row + posrel rank-3 update ----------------
__global__ __launch_bounds__(256) void lin_in_kernel(
    const float* __restrict__ EW, const float* __restrict__ posrel,
    const int* __restrict__ zidx, const float* __restrict__ lin_w,
    unsigned short* __restrict__ xhi, unsigned short* __restrict__ xlo)
{
    const int tid = threadIdx.x;
    const int node = blockIdx.x * 16 + (tid >> 4);
    const int j0 = (tid & 15) * 8;

    const int zz = zidx[node];
    const float px = posrel[node*3+0], py = posrel[node*3+1], pz = posrel[node*3+2];

    const float4 e0 = *(const float4*)&EW[zz*128 + j0];
    const float4 e1 = *(const float4*)&EW[zz*128 + j0 + 4];
    const float4 wx0 = *(const float4*)&lin_w[128*128 + j0];
    const float4 wx1 = *(const float4*)&lin_w[128*128 + j0 + 4];
    const float4 wy0 = *(const float4*)&lin_w[129*128 + j0];
    const float4 wy1 = *(const float4*)&lin_w[129*128 + j0 + 4];
    const float4 wz0 = *(const float4*)&lin_w[130*128 + j0];
    const float4 wz1 = *(const float4*)&lin_w[130*128 + j0 + 4];

    float o[8];
    o[0] = e0.x + px*wx0.x + py*wy0.x + pz*wz0.x;
    o[1] = e0.y + px*wx0.y + py*wy0.y + pz*wz0.y;
    o[2] = e0.z + px*wx0.z + py*wy0.z + pz*wz0.z;
    o[3] = e0.w + px*wx0.w + py*wy0.w + pz*wz0.w;
    o[4] = e1.x + px*wx1.x + py*wy1.x + pz*wz1.x;
    o[5] = e1.y + px*wx1.y + py*wy1.y + pz*wz1.y;
    o[6] = e1.z + px*wx1.z + py*wy1.z + pz*wz1.z;
    o[7] = e1.w + px*wx1.w + py*wy1.w + pz*wz1.w;

    ushort4 h0, l0, h1, l1;
    split2(o[0], h0.x, l0.x); split2(o[1], h0.y, l0.y);
    split2(o[2], h0.z, l0.z); split2(o[3], h0.w, l0.w);
    split2(o[4], h1.x, l1.x); split2(o[5], h1.y, l1.y);
    split2(o[6], h1.z, l1.z); split2(o[7], h1.w, l1.w);
    *(ushort4*)&xhi[node*HD + j0]     = h0;
    *(ushort4*)&xhi[node*HD + j0 + 4] = h1;
    *(ushort4*)&xlo[node*HD + j0]     = l0;
    *(ushort4*)&xlo[node*HD + j0 + 4] = l1;
}

// ---------------- pq GEMM (MFMA swapped-operand: per-lane 4 consecutive cols) --------
// Q outputs get b1 folded in (fp32 add before fp16 round).
__global__ __launch_bounds__(256) void pq_gemm(
    const unsigned short* __restrict__ xhi, const unsigned short* __restrict__ xlo,
    const unsigned short* __restrict__ w1th, const unsigned short* __restrict__ w1tl,
    unsigned short* __restrict__ Ph, unsigned short* __restrict__ Qh,
    float* __restrict__ msum, const float* __restrict__ b1)
{
    const int tid = threadIdx.x;
    const int l = tid & 63, w = tid >> 6;
    const int mr = l & 15, qd = l >> 4;
    const int n0 = blockIdx.x * 64;
    const int c0 = w * 64;

    // fused msum zeroing: this block owns a 32 KB slice (8192 floats = 2048 float4)
    {
        float4* mz = (float4*)&msum[(long)blockIdx.x * 8192];
        const float4 z4 = make_float4(0.f, 0.f, 0.f, 0.f);
        #pragma unroll
        for (int it = 0; it < 8; ++it) mz[tid + it*256] = z4;
    }

    f32x4 acc[4][4];
    #pragma unroll
    for (int mt = 0; mt < 4; ++mt)
        #pragma unroll
        for (int nt = 0; nt < 4; ++nt) acc[mt][nt] = (f32x4){0.f,0.f,0.f,0.f};

    #pragma unroll
    for (int ks = 0; ks < 4; ++ks) {
        const int kof = ks*32 + qd*8;
        const int kb  = ks*4 + qd;
        bf16x8 ah[4], al[4], bh[4], bl[4];
        #pragma unroll
        for (int mt = 0; mt < 4; ++mt) {
            const int node = n0 + mt*16 + mr;
            ah[mt] = *(const bf16x8*)&xhi[node*HD + kof];
            al[mt] = *(const bf16x8*)&xlo[node*HD + kof];
        }
        #pragma unroll
        for (int nt = 0; nt < 4; ++nt) {
            const int c = c0 + nt*16 + mr;
            bh[nt] = *(const bf16x8*)&w1th[(kb << 11) + (c << 3)];
            bl[nt] = *(const bf16x8*)&w1tl[(kb << 11) + (c << 3)];
        }
        // swapped operands: D^T fragment — row=reg ↔ weight col, col=lane ↔ node
        #pragma unroll
        for (int mt = 0; mt < 4; ++mt)
            #pragma unroll
            for (int nt = 0; nt < 4; ++nt) {
                acc[mt][nt] = __builtin_amdgcn_mfma_f32_16x16x32_bf16(bh[nt], ah[mt], acc[mt][nt], 0,0,0);
                acc[mt][nt] = __builtin_amdgcn_mfma_f32_16x16x32_bf16(bl[nt], ah[mt], acc[mt][nt], 0,0,0);
                acc[mt][nt] = __builtin_amdgcn_mfma_f32_16x16x32_bf16(bh[nt], al[mt], acc[mt][nt], 0,0,0);
            }
    }

    unsigned short* __restrict__ dst = (w < 2) ? Ph : Qh;
    const int cbase = (w < 2) ? c0 : c0 - 128;
    #pragma unroll
    for (int mt = 0; mt < 4; ++mt) {
        const int node = n0 + mt*16 + mr;
        #pragma unroll
        for (int nt = 0; nt < 4; ++nt) {
            const int ccb = cbase + nt*16 + qd*4;    // 4 consecutive columns per lane
            float4 bb4 = make_float4(0.f, 0.f, 0.f, 0.f);
            if (w >= 2) bb4 = *(const float4*)&b1[ccb];
            ushort4 o4;
            o4.x = f2h(acc[mt][nt][0] + bb4.x);
            o4.y = f2h(acc[mt][nt][1] + bb4.y);
            o4.z = f2h(acc[mt][nt][2] + bb4.z);
            o4.w = f2h(acc[mt][nt][3] + bb4.w);
            *(ushort4*)&dst[(long)node*HD + ccb] = o4;
        }
    }
}

// ---------------- update GEMM (MFMA swapped-operand, packed-coalesced B) -------------
__global__ __launch_bounds__(256) void upd_gemm(
    unsigned short* __restrict__ xhi, unsigned short* __restrict__ xlo,
    const float* __restrict__ msum, const int* __restrict__ degi,
    const unsigned short* __restrict__ wuth, const unsigned short* __restrict__ wutl,
    const float* __restrict__ bias)
{
    const int tid = threadIdx.x;
    const int l = tid & 63, w = tid >> 6;
    const int mr = l & 15, qd = l >> 4;
    const int n0 = blockIdx.x * 64 + w*16;
    const int node = n0 + mr;
    const float inv = 1.f / fmaxf((float)degi[node], 1.f);

    f32x4 acc[8];
    #pragma unroll
    for (int nt = 0; nt < 8; ++nt) acc[nt] = (f32x4){0.f,0.f,0.f,0.f};

    #pragma unroll 1
    for (int ks = 0; ks < 8; ++ks) {
        const int kof = ks*32 + qd*8;
        const int kb  = ks*4 + qd;
        bf16x8 ah, al;
        if (ks < 4) {
            ah = *(const bf16x8*)&xhi[node*HD + kof];
            al = *(const bf16x8*)&xlo[node*HD + kof];
        } else {
            const int mk = kof - 128;
            const float4 v0 = *(const float4*)&msum[(long)node*HD + mk];
            const float4 v1 = *(const float4*)&msum[(long)node*HD + mk + 4];
            union { bf16x8 v; unsigned short u[8]; } hh, ll;
            float vv[8] = { v0.x*inv, v0.y*inv, v0.z*inv, v0.w*inv,
                            v1.x*inv, v1.y*inv, v1.z*inv, v1.w*inv };
            #pragma unroll
            for (int i = 0; i < 8; ++i) split2(vv[i], hh.u[i], ll.u[i]);
            ah = hh.v; al = ll.v;
        }
        #pragma unroll
        for (int nt = 0; nt < 8; ++nt) {
            const int c = nt*16 + mr;
            const bf16x8 bh = *(const bf16x8*)&wuth[(kb << 10) + (c << 3)];
            const bf16x8 bl = *(const bf16x8*)&wutl[(kb << 10) + (c << 3)];
            acc[nt] = __builtin_amdgcn_mfma_f32_16x16x32_bf16(bh, ah, acc[nt], 0,0,0);
            acc[nt] = __builtin_amdgcn_mfma_f32_16x16x32_bf16(bl, ah, acc[nt], 0,0,0);
            acc[nt] = __builtin_amdgcn_mfma_f32_16x16x32_bf16(bh, al, acc[nt], 0,0,0);
        }
    }

    // D^T layout: this lane owns node = n0+mr, columns nt*16 + qd*4 + 0..3
    #pragma unroll
    for (int nt = 0; nt < 8; ++nt) {
        const int cb = nt*16 + qd*4;
        const float4 bb4 = *(const float4*)&bias[cb];
        float o0 = fmaxf(acc[nt][0] + bb4.x, 0.f);
        float o1 = fmaxf(acc[nt][1] + bb4.y, 0.f);
        float o2 = fmaxf(acc[nt][2] + bb4.z, 0.f);
        float o3 = fmaxf(acc[nt][3] + bb4.w, 0.f);
        ushort4 h4, l4;
        split2(o0, h4.x, l4.x); split2(o1, h4.y, l4.y);
        split2(o2, h4.z, l4.z); split2(o3, h4.w, l4.w);
        *(ushort4*)&xhi[(long)node*HD + cb] = h4;
        *(ushort4*)&xlo[(long)node*HD + cb] = l4;
    }
}

// ---------------- fused edge kernel: 512 threads share one W2 LDS copy --------------
// Per-wave code identical to the round-8 best-known form; 8 waves/block raises the
// static occupancy ceiling (min(LDS 40, VGPR 24, slots 32) = 24 waves/CU vs 20) and
// halves the W2 staging traffic. TLP-bound regime: throughput tracks resident waves.
__global__ __launch_bounds__(512, 2) void edge_msg_kernel(
    const unsigned short* __restrict__ Ph, const unsigned short* __restrict__ Qh,
    const uint2* __restrict__ rcD,
    const unsigned short* __restrict__ c1h,   // fp16 [128] dist-col of W1 (layer slice)
    const unsigned short* __restrict__ w2t,   // fp16, swizzled 16B-block layout
    const float* __restrict__ b2,
    float* __restrict__ msum)
{
    __shared__ __align__(16) unsigned short w2s[16384];   // 32 KB, shared by 8 waves
    const int tid = threadIdx.x;

    // ---- stage W2 slice into LDS (global layout == LDS layout, linear copy) ----
    {
        const uint4* __restrict__ src = (const uint4*)w2t;
        uint4* dst = (uint4*)w2s;
        #pragma unroll
        for (int i = 0; i < 4; ++i) dst[tid + i*512] = src[tid + i*512];
    }

    const long e0 = (long)blockIdx.x * 512;
    const int l  = tid & 63;
    const int w  = tid >> 6;            // 0..7
    const int mr = l & 15;
    const int qd = l >> 4;
    const long ebase = e0 + w*64;

    const int aoff = ((mr >> 2) << 4) + (mr & 3);
    int ecol[4], erow[4];
    float edist[4];
    #pragma unroll
    for (int m = 0; m < 4; ++m) {
        const uint2 rd = rcD[ebase + aoff + m*4];
        erow[m] = (int)(rd.x >> 16); ecol[m] = (int)(rd.x & 0xffffu);
        edist[m] = __uint_as_float(rd.y);
    }

    // ---- issue ALL 16 random P gathers first (the long-latency stream) ----
    u16x8 praw[4][4];
    #pragma unroll
    for (int m = 0; m < 4; ++m)
        #pragma unroll
        for (int kk = 0; kk < 4; ++kk)
            praw[m][kk] = *(const u16x8*)&Ph[(long)ecol[m]*HD + kk*32 + qd*8];

    unsigned rcv[16];
    {
        const uint4* rc4 = (const uint4*)&rcD[ebase + qd*16];   // uint4 = 2 edges
        #pragma unroll
        for (int i = 0; i < 8; ++i) {
            const uint4 v = rc4[i];
            rcv[i*2+0] = (v.x >> 16) << 7;
            rcv[i*2+1] = (v.z >> 16) << 7;
        }
    }
    // run-boundary mask, computed ONCE (rows invariant across t-loop)
    unsigned sameMask = 0;
    #pragma unroll
    for (int i = 1; i < 16; ++i) if (rcv[i] == rcv[i-1]) sameMask |= (1u << i);

    // preload ALL per-t biases (kills the in-loop vmem load)
    float b2v[8];
    #pragma unroll
    for (int t = 0; t < 8; ++t) b2v[t] = b2[t*16 + mr];

    // uniform fp16 dist-column (precomputed in wprep — no per-lane cvts)
    f16x8 c8[4];
    #pragma unroll
    for (int kk = 0; kk < 4; ++kk) {
        union { u16x8 raw; f16x8 v; } cu;
        cu.raw = ((const u16x8*)c1h)[kk*4 + qd];
        c8[kk] = cu.v;
    }

    // ---- phase 1: H fragments in packed fp16 (b1 already folded into Q) ----
    const f16x8 z8 = {};
    f16x8 afr[4][4];
    #pragma unroll
    for (int m = 0; m < 4; ++m) {
        union { u16x8 raw; f16x8 v; } qu[4];
        #pragma unroll
        for (int kk = 0; kk < 4; ++kk)
            qu[kk].raw = *(const u16x8*)&Qh[(long)erow[m]*HD + kk*32 + qd*8];
        const _Float16 d16 = (_Float16)edist[m];
        #pragma unroll
        for (int kk = 0; kk < 4; ++kk) {
            union { u16x8 raw; f16x8 v; } pu; pu.raw = praw[m][kk];
            f16x8 s = pu.v + qu[kk].v + d16 * c8[kk];
            afr[m][kk] = __builtin_elementwise_max(s, z8);
        }
    }

    __syncthreads();   // W2 staging complete (overlapped with gathers above)

    // ---- t-loop: ds_read (lgkmcnt) + MFMA + atomics only — no vmem loads ----
    #pragma unroll 1
    for (int t = 0; t < 8; ++t) {
        f16x8 bfr[4];
        #pragma unroll
        for (int kk = 0; kk < 4; ++kk) {
            const int c = kk*4 + qd;
            const int blk = (t*16 + mr)*16 + (c ^ (mr & 7));
            union { u16x8 raw; f16x8 v; } bu;
            bu.raw = *(const u16x8*)&w2s[blk*8];
            bfr[kk] = bu.v;
        }
        const int colg = t*16 + mr;
        const float bb = b2v[t];

        f32x4 acc[4];
        #pragma unroll
        for (int m = 0; m < 4; ++m) acc[m] = (f32x4){0.f, 0.f, 0.f, 0.f};
        #pragma unroll
        for (int kk = 0; kk < 4; ++kk)
            #pragma unroll
            for (int m = 0; m < 4; ++m)
                acc[m] = __builtin_amdgcn_mfma_f32_16x16x32_f16(afr[m][kk], bfr[kk], acc[m], 0, 0, 0);

        // branchless run accumulation; atomic only at run boundaries
        float run = 0.f;
        #pragma unroll
        for (int i = 0; i < 16; ++i) {
            const float v = fmaxf(acc[i>>2][i&3] + bb, 0.f);
            run = (sameMask & (1u << i)) ? run + v : v;
            if (!(sameMask & (2u << i)))        // next row differs (bit16 is 0 -> i==15 flushes)
                atomAdd(&msum[(long)(rcv[i] + colg)], run);
        }
    }
}

// ---------------- ligand-masked per-graph sum: batch-sorted run aggregation --------------
__global__ __launch_bounds__(256) void gsum_kernel(
    const unsigned short* __restrict__ xhi, const unsigned short* __restrict__ xlo,
    const int* __restrict__ batch,
    const int* __restrict__ ntype, float* __restrict__ gsum)
{
    const int tid = threadIdx.x;
    const int cg = tid & 31;          // float4 col group
    const int ns = tid >> 5;          // node strip 0..7
    const int n0 = blockIdx.x * 512 + ns * 64;

    int bprev = -1;
    float4 run = make_float4(0.f, 0.f, 0.f, 0.f);
    for (int i = 0; i < 64; ++i) {
        const int n = n0 + i;
        if (ntype[n] != 1) continue;
        const int b = batch[n];
        const ushort4 h  = *(const ushort4*)&xhi[(long)n*HD + cg*4];
        const ushort4 lo = *(const ushort4*)&xlo[(long)n*HD + cg*4];
        float4 v;
        v.x = bf2f(h.x) + bf2f(lo.x);
        v.y = bf2f(h.y) + bf2f(lo.y);
        v.z = bf2f(h.z) + bf2f(lo.z);
        v.w = bf2f(h.w) + bf2f(lo.w);
        if (b != bprev) {
            if (bprev >= 0) {
                float* dst = &gsum[bprev*HD + cg*4];
                atomAdd(dst+0, run.x); atomAdd(dst+1, run.y);
                atomAdd(dst+2, run.z); atomAdd(dst+3, run.w);
            }
            bprev = b; run = v;
        } else {
            run.x += v.x; run.y += v.y; run.z += v.z; run.w += v.w;
        }
    }
    if (bprev >= 0) {
        float* dst = &gsum[bprev*HD + cg*4];
        atomAdd(dst+0, run.x); atomAdd(dst+1, run.y);
        atomAdd(dst+2, run.z); atomAdd(dst+3, run.w);
    }
}

// ---------------- readout ----------------
__global__ __launch_bounds__(128) void readout_kernel(
    const float* __restrict__ gsum, const float* __restrict__ lcnt,
    const float* __restrict__ w1, const float* __restrict__ b1,
    const float* __restrict__ w2, const float* __restrict__ b2,
    float* __restrict__ out)
{
    __shared__ float gs[HD];
    __shared__ float red[2];
    const int b = blockIdx.x, j = threadIdx.x;
    gs[j] = gsum[b*HD + j] / fmaxf(lcnt[b], 1.f);
    __syncthreads();
    float acc = b1[j];
    for (int k = 0; k < HD; ++k) acc += gs[k]*w1[k*HD + j];
    float hg = fmaxf(acc, 0.f) * w2[j];
    #pragma unroll
    for (int off = 32; off > 0; off >>= 1) hg += __shfl_down(hg, off, 64);
    if ((j & 63) == 0) red[j >> 6] = hg;
    __syncthreads();
    if (j == 0) out[b] = red[0] + red[1] + b2[0];
}

extern "C" void kernel_launch(void* const* d_in, const int* in_sizes, int n_in,
                              void* d_out, int out_size, void* d_ws, size_t ws_size,
                              hipStream_t stream)
{
    const float* pos   = (const float*)d_in[0];
    const int*   z     = (const int*)d_in[1];
    const int*   batch = (const int*)d_in[2];
    const int*   eidx  = (const int*)d_in[3];
    const int*   ntype = (const int*)d_in[4];
    const float* emb   = (const float*)d_in[5];
    const float* lin_w = (const float*)d_in[6];
    const float* lin_b = (const float*)d_in[7];
    const float* mw1   = (const float*)d_in[8];
    const float* mb1   = (const float*)d_in[9];
    const float* mw2   = (const float*)d_in[10];
    const float* mb2   = (const float*)d_in[11];
    const float* uw    = (const float*)d_in[12];
    const float* ub    = (const float*)d_in[13];
    const float* rw1   = (const float*)d_in[14];
    const float* rb1   = (const float*)d_in[15];
    const float* rw2   = (const float*)d_in[16];
    const float* rb2   = (const float*)d_in[17];

    const int* row = eidx;
    const int* col = eidx + NE;

    float* ws     = (float*)d_ws;
    float* csum   = ws + O_CSUM;
    float* ccnt   = ws + O_CCNT;
    float* lcnt   = ws + O_LCNT;
    float* gsum   = ws + O_GSUM;
    int*   degi   = (int*)(ws + O_DEGI);
    float* posrel = ws + O_POSREL;
    unsigned short* xhi = (unsigned short*)(ws + O_XHI);
    unsigned short* xlo = (unsigned short*)(ws + O_XLO);
    unsigned short* Ph  = (unsigned short*)(ws + O_P);
    uint2* rcD    = (uint2*)(ws + O_RCD);
    unsigned short* Qh  = (unsigned short*)(ws + O_Q);
    unsigned short* c1h = (unsigned short*)(ws + O_C1H);
    float* EW     = ws + O_EW;
    float* msum   = ws + O_MSUM;
    unsigned short* w2t  = (unsigned short*)(ws + O_W2T);
    unsigned short* w1th = (unsigned short*)(ws + O_W1TH);
    unsigned short* w1tl = (unsigned short*)(ws + O_W1TL);
    unsigned short* wuth = (unsigned short*)(ws + O_WUTH);
    unsigned short* wutl = (unsigned short*)(ws + O_WUTL);
    int* chunkSum = (int*)(ws + O_CHK);
    int* rowStart = (int*)xhi;           // alias xhi head pre-lin_in
    int* cnt      = (int*)xhi + NN;

    (void)hipMemsetAsync(ws, 0, (size_t)(O_DEGI + NN) * sizeof(float), stream);
    (void)hipMemsetAsync(cnt, 0, (size_t)NN * sizeof(int), stream);

    stats_kernel  <<<NN/256, 256, 0, stream>>>(pos, batch, ntype, csum, ccnt, lcnt);
    deg_kernel    <<<NE/256, 256, 0, stream>>>(row, degi);
    posrel_kernel <<<NN/256, 256, 0, stream>>>(pos, batch, csum, ccnt, posrel);
    scanA_kernel  <<<256, 256, 0, stream>>>(degi, chunkSum);
    scanB_kernel  <<<1, 256, 0, stream>>>(chunkSum);
    scanC_kernel  <<<256, 256, 0, stream>>>(degi, chunkSum, rowStart);
    scatter_kernel<<<NE/256, 256, 0, stream>>>(row, col, rowStart, cnt, rcD, posrel);
    wprep_kernel  <<<384, 256, 0, stream>>>(mw1, uw, mw2, lin_w, lin_b, emb,
                                            w1th, w1tl, wuth, wutl, w2t, c1h, EW);

    lin_in_kernel<<<NN/16, 256, 0, stream>>>(EW, posrel, z, lin_w, xhi, xlo);

    for (int l = 0; l < NL; ++l) {
        pq_gemm<<<NN/64, 256, 0, stream>>>(xhi, xlo,
                                           w1th + (size_t)l*32768, w1tl + (size_t)l*32768,
                                           Ph, Qh, msum, mb1 + (size_t)l*HD);
        edge_msg_kernel<<<NE/512, 512, 0, stream>>>(Ph, Qh, rcD,
                                                    c1h + (size_t)l*HD,
                                                    w2t + (size_t)l*16384, mb2 + l*HD, msum);
        upd_gemm<<<NN/64, 256, 0, stream>>>(xhi, xlo, msum, degi,
                                            wuth + (size_t)l*32768, wutl + (size_t)l*32768,
                                            ub + l*HD);
    }

    gsum_kernel   <<<NN/512, 256, 0, stream>>>(xhi, xlo, batch, ntype, gsum);
    readout_kernel<<<NB, 128, 0, stream>>>(gsum, lcnt, rw1, rb1, rw2, rb2, (float*)d_out);
}

// Round 12
// 693.446 us; speedup vs baseline: 1.1684x; 1.1684x over previous
//
#include <hip/hip_runtime.h>
#include <hip/hip_bf16.h>
#include <hip/hip_fp16.h>
#include <math.h>

#define NN 65536
#define NE 1048576
#define NB 64
#define HD 128
#define NL 3

// ---- workspace layout (float offsets) ----
#define O_CSUM   0
#define O_CCNT   192
#define O_LCNT   256
#define O_GSUM   320         // -> 8512
#define O_DEGI   8512        // -> 74048
#define O_POSREL 74048       // -> 270656
#define O_RC     270656      // (unused now) -> 1319232
#define O_XHI    1319232     // NN*128 ushort -> 5513536
#define O_XLO    5513536     // -> 9707840
#define O_P      9707840     // NN*128 fp16 -> 13902144 used; region to 18096448
#define O_RCD    13902144    // uint2[NE] (rc, dist) -> 15999296 (O_P slack)
#define O_Q      18096448    // NN*128 fp16 -> 22290752 used; region to 26485056
#define O_C1H    22290752    // fp16 [3][128] dist-col of W1 -> 22290944
#define O_EW     22291456    // fp32 [100][128] emb@W + b -> 22304256 (Q-region slack)
#define O_MSUM   26485056    // -> 34873664
#define O_W2T    34873664    // 3*128*128 fp16 (SWIZZLED layout) -> 34898240
#define O_W1TH   34898240    // -> 34947392   (packed [l][kb16][c256][8])
#define O_W1TL   34947392    // -> 34996544
#define O_WUTH   34996544    // -> 35045696   (packed [l][kb32][c128][8])
#define O_WUTL   35045696    // -> 35094848
#define O_CHK    35094848    // 256 ints -> 35095104 (~140.4 MB)

typedef __attribute__((ext_vector_type(8))) short bf16x8;
typedef __attribute__((ext_vector_type(8))) _Float16 f16x8;
typedef __attribute__((ext_vector_type(8))) unsigned short u16x8;
typedef __attribute__((ext_vector_type(4))) float f32x4;

__device__ __forceinline__ void atomAdd(float* p, float v) { unsafeAtomicAdd(p, v); }

__device__ __forceinline__ unsigned short f2bf(float f) {
    union { __hip_bfloat16 h; unsigned short u; } cv;
    cv.h = __float2bfloat16(f);
    return cv.u;
}
__device__ __forceinline__ float bf2f(unsigned short u) {
    union { float f; unsigned v; } c; c.v = ((unsigned)u) << 16; return c.f;
}
__device__ __forceinline__ void split2(float v, unsigned short& h, unsigned short& l) {
    h = f2bf(v); l = f2bf(v - bf2f(h));
}
__device__ __forceinline__ unsigned short f2h(float f) {
    union { __half h; unsigned short u; } c; c.h = __float2half(f); return c.u;
}

// ---------------- stats ----------------
__global__ __launch_bounds__(256) void stats_kernel(
    const float* __restrict__ pos, const int* __restrict__ batch,
    const int* __restrict__ ntype,
    float* __restrict__ csum, float* __restrict__ ccnt, float* __restrict__ lcnt)
{
    __shared__ float s[NB * 5];
    const int tid = threadIdx.x;
    for (int i = tid; i < NB * 5; i += 256) s[i] = 0.f;
    __syncthreads();
    const int n = blockIdx.x * 256 + tid;
    const int b = batch[n];
    atomicAdd(&s[b*5+0], pos[n*3+0]);
    atomicAdd(&s[b*5+1], pos[n*3+1]);
    atomicAdd(&s[b*5+2], pos[n*3+2]);
    atomicAdd(&s[b*5+3], 1.f);
    if (ntype[n] == 1) atomicAdd(&s[b*5+4], 1.f);
    __syncthreads();
    for (int i = tid; i < NB * 5; i += 256) {
        float v = s[i];
        if (v != 0.f) {
            int b2 = i / 5, f = i - b2*5;
            if (f < 3)       atomAdd(&csum[b2*3+f], v);
            else if (f == 3) atomAdd(&ccnt[b2], v);
            else             atomAdd(&lcnt[b2], v);
        }
    }
}

// ---------------- degree histogram ----------------
__global__ __launch_bounds__(256) void deg_kernel(const int* __restrict__ row, int* __restrict__ degi)
{
    const int e = blockIdx.x * 256 + threadIdx.x;
    atomicAdd(&degi[row[e]], 1);
}

// ---------------- two-level scan ----------------
__global__ __launch_bounds__(256) void scanA_kernel(const int* __restrict__ degi, int* __restrict__ chunkSum)
{
    __shared__ int red[4];
    const int t = threadIdx.x, b = blockIdx.x;
    int v = degi[b*256 + t];
    #pragma unroll
    for (int off = 32; off > 0; off >>= 1) v += __shfl_down(v, off, 64);
    if ((t & 63) == 0) red[t >> 6] = v;
    __syncthreads();
    if (t == 0) chunkSum[b] = red[0] + red[1] + red[2] + red[3];
}

__global__ __launch_bounds__(256) void scanB_kernel(int* __restrict__ chunkSum)
{
    __shared__ int s[256];
    const int t = threadIdx.x;
    const int v = chunkSum[t];
    s[t] = v;
    __syncthreads();
    #pragma unroll
    for (int off = 1; off < 256; off <<= 1) {
        int u = (t >= off) ? s[t - off] : 0;
        __syncthreads();
        s[t] += u;
        __syncthreads();
    }
    chunkSum[t] = s[t] - v;   // exclusive
}

__global__ __launch_bounds__(256) void scanC_kernel(const int* __restrict__ degi,
                                                    const int* __restrict__ chunkOff,
                                                    int* __restrict__ rowStart)
{
    __shared__ int s[256];
    const int t = threadIdx.x, b = blockIdx.x;
    const int v = degi[b*256 + t];
    s[t] = v;
    __syncthreads();
    #pragma unroll
    for (int off = 1; off < 256; off <<= 1) {
        int u = (t >= off) ? s[t - off] : 0;
        __syncthreads();
        s[t] += u;
        __syncthreads();
    }
    rowStart[b*256 + t] = chunkOff[b] + s[t] - v;
}

// ---------------- counting-sort scatter: single 8B store per edge (rc + dist) --------
__global__ __launch_bounds__(256) void scatter_kernel(
    const int* __restrict__ row, const int* __restrict__ col,
    const int* __restrict__ rowStart, int* __restrict__ cnt,
    uint2* __restrict__ rcD,
    const float* __restrict__ posrel)
{
    const int e = blockIdx.x * 256 + threadIdx.x;
    const int r = row[e], c = col[e];
    const float dx = posrel[c*3+0] - posrel[r*3+0];
    const float dy = posrel[c*3+1] - posrel[r*3+1];
    const float dz = posrel[c*3+2] - posrel[r*3+2];
    const float dist = sqrtf(dx*dx + dy*dy + dz*dz);
    const int p = rowStart[r] + atomicAdd(&cnt[r], 1);
    rcD[p] = make_uint2(((unsigned)r << 16) | (unsigned)c, __float_as_uint(dist));
}

// ---------------- pos_rel ----------------
__global__ __launch_bounds__(256) void posrel_kernel(
    const float* __restrict__ pos, const int* __restrict__ batch,
    const float* __restrict__ csum, const float* __restrict__ ccnt,
    float* __restrict__ posrel)
{
    const int n = blockIdx.x * 256 + threadIdx.x;
    const int b = batch[n];
    const float inv = 1.f / fmaxf(ccnt[b], 1.f);
    posrel[n*3+0] = pos[n*3+0] - csum[b*3+0]*inv;
    posrel[n*3+1] = pos[n*3+1] - csum[b*3+1]*inv;
    posrel[n*3+2] = pos[n*3+2] - csum[b*3+2]*inv;
}

// ---------------- weight prep: packed split-bf16 ([kb][c][8]) + W2T swz + c1h + EW ----
__global__ __launch_bounds__(256) void wprep_kernel(
    const float* __restrict__ mw1, const float* __restrict__ uw,
    const float* __restrict__ mw2,
    const float* __restrict__ lin_w, const float* __restrict__ lin_b,
    const float* __restrict__ emb,
    unsigned short* __restrict__ w1th, unsigned short* __restrict__ w1tl,
    unsigned short* __restrict__ wuth, unsigned short* __restrict__ wutl,
    unsigned short* __restrict__ w2t, unsigned short* __restrict__ c1h,
    float* __restrict__ EW)
{
    const int idx = blockIdx.x * 256 + threadIdx.x;   // 98304
    {   // W1T packed: [l][kb 0..15][c 0..255][w 0..7]; element = W1T[l][c][kb*8+w]
        const int l = idx >> 15, rem = idx & 32767;
        const int w = rem & 7, t = rem >> 3;
        const int c = t & 255, kb = t >> 8;
        const int k = kb*8 + w;
        const int kk = (c < 128) ? k : (128 + k);
        const int cc = c & 127;
        const float v = mw1[l*257*128 + kk*128 + cc];
        unsigned short h, lo; split2(v, h, lo);
        w1th[idx] = h; w1tl[idx] = lo;
    }
    {   // WuT packed: [l][kb 0..31][c 0..127][w 0..7]; element = uw[l][kb*8+w][c]
        const int l = idx >> 15, rem = idx & 32767;
        const int w = rem & 7, t = rem >> 3;
        const int c = t & 127, kb = t >> 7;
        const int k = kb*8 + w;
        const float v = uw[l*256*128 + k*128 + c];
        unsigned short h, lo; split2(v, h, lo);
        wuth[idx] = h; wutl[idx] = lo;
    }
    if (idx < 49152) {
        // W2T fp16, XOR-swizzled 16B blocks: position blk=(n*16+cs) holds logical
        // (n, c = cs ^ (n&7)) so LDS ds_read_b128 at n*16 + (c^(n&7)) is conflict-free.
        const int l = idx >> 14, rem = idx & 16383;
        const int blk = rem >> 3, win = rem & 7;
        const int n = blk >> 4, cs = blk & 15;
        const int c = cs ^ (n & 7);
        const int k = c*8 + win;
        w2t[idx] = f2h(mw2[(l << 14) + k*128 + n]);
    }
    if (idx < 384) {     // c1h fp16: dist column (row 256) of W1, [l][c]
        const int l = idx >> 7, c = idx & 127;
        c1h[idx] = f2h(mw1[l*257*128 + 256*128 + c]);
    }
    if (idx < 12800) {   // EW = emb(100x128) @ lin_w[:128] + lin_b   (exact fp32)
        const int j = idx & 127, zz = idx >> 7;
        float acc = lin_b[j];
        for (int k = 0; k < 128; ++k)
            acc += emb[zz*128 + k] * lin_w[k*128 + j];
        EW[idx] = acc;
    }
}

// ---------------- lin_in: gather EW row + posrel rank-3 update ----------------
__global__ __launch_bounds__(256) void lin_in_kernel(
    const float* __restrict__ EW, const float* __restrict__ posrel,
    const int* __restrict__ zidx, const float* __restrict__ lin_w,
    unsigned short* __restrict__ xhi, unsigned short* __restrict__ xlo)
{
    const int tid = threadIdx.x;
    const int node = blockIdx.x * 16 + (tid >> 4);
    const int j0 = (tid & 15) * 8;

    const int zz = zidx[node];
    const float px = posrel[node*3+0], py = posrel[node*3+1], pz = posrel[node*3+2];

    const float4 e0 = *(const float4*)&EW[zz*128 + j0];
    const float4 e1 = *(const float4*)&EW[zz*128 + j0 + 4];
    const float4 wx0 = *(const float4*)&lin_w[128*128 + j0];
    const float4 wx1 = *(const float4*)&lin_w[128*128 + j0 + 4];
    const float4 wy0 = *(const float4*)&lin_w[129*128 + j0];
    const float4 wy1 = *(const float4*)&lin_w[129*128 + j0 + 4];
    const float4 wz0 = *(const float4*)&lin_w[130*128 + j0];
    const float4 wz1 = *(const float4*)&lin_w[130*128 + j0 + 4];

    float o[8];
    o[0] = e0.x + px*wx0.x + py*wy0.x + pz*wz0.x;
    o[1] = e0.y + px*wx0.y + py*wy0.y + pz*wz0.y;
    o[2] = e0.z + px*wx0.z + py*wy0.z + pz*wz0.z;
    o[3] = e0.w + px*wx0.w + py*wy0.w + pz*wz0.w;
    o[4] = e1.x + px*wx1.x + py*wy1.x + pz*wz1.x;
    o[5] = e1.y + px*wx1.y + py*wy1.y + pz*wz1.y;
    o[6] = e1.z + px*wx1.z + py*wy1.z + pz*wz1.z;
    o[7] = e1.w + px*wx1.w + py*wy1.w + pz*wz1.w;

    ushort4 h0, l0, h1, l1;
    split2(o[0], h0.x, l0.x); split2(o[1], h0.y, l0.y);
    split2(o[2], h0.z, l0.z); split2(o[3], h0.w, l0.w);
    split2(o[4], h1.x, l1.x); split2(o[5], h1.y, l1.y);
    split2(o[6], h1.z, l1.z); split2(o[7], h1.w, l1.w);
    *(ushort4*)&xhi[node*HD + j0]     = h0;
    *(ushort4*)&xhi[node*HD + j0 + 4] = h1;
    *(ushort4*)&xlo[node*HD + j0]     = l0;
    *(ushort4*)&xlo[node*HD + j0 + 4] = l1;
}

// ---------------- pq GEMM (MFMA swapped-operand: per-lane 4 consecutive cols) --------
// Q outputs get b1 folded in (fp32 add before fp16 round).
__global__ __launch_bounds__(256) void pq_gemm(
    const unsigned short* __restrict__ xhi, const unsigned short* __restrict__ xlo,
    const unsigned short* __restrict__ w1th, const unsigned short* __restrict__ w1tl,
    unsigned short* __restrict__ Ph, unsigned short* __restrict__ Qh,
    float* __restrict__ msum, const float* __restrict__ b1)
{
    const int tid = threadIdx.x;
    const int l = tid & 63, w = tid >> 6;
    const int mr = l & 15, qd = l >> 4;
    const int n0 = blockIdx.x * 64;
    const int c0 = w * 64;

    // fused msum zeroing: this block owns a 32 KB slice (8192 floats = 2048 float4)
    {
        float4* mz = (float4*)&msum[(long)blockIdx.x * 8192];
        const float4 z4 = make_float4(0.f, 0.f, 0.f, 0.f);
        #pragma unroll
        for (int it = 0; it < 8; ++it) mz[tid + it*256] = z4;
    }

    f32x4 acc[4][4];
    #pragma unroll
    for (int mt = 0; mt < 4; ++mt)
        #pragma unroll
        for (int nt = 0; nt < 4; ++nt) acc[mt][nt] = (f32x4){0.f,0.f,0.f,0.f};

    #pragma unroll
    for (int ks = 0; ks < 4; ++ks) {
        const int kof = ks*32 + qd*8;
        const int kb  = ks*4 + qd;
        bf16x8 ah[4], al[4], bh[4], bl[4];
        #pragma unroll
        for (int mt = 0; mt < 4; ++mt) {
            const int node = n0 + mt*16 + mr;
            ah[mt] = *(const bf16x8*)&xhi[node*HD + kof];
            al[mt] = *(const bf16x8*)&xlo[node*HD + kof];
        }
        #pragma unroll
        for (int nt = 0; nt < 4; ++nt) {
            const int c = c0 + nt*16 + mr;
            bh[nt] = *(const bf16x8*)&w1th[(kb << 11) + (c << 3)];
            bl[nt] = *(const bf16x8*)&w1tl[(kb << 11) + (c << 3)];
        }
        // swapped operands: D^T fragment — row=reg ↔ weight col, col=lane ↔ node
        #pragma unroll
        for (int mt = 0; mt < 4; ++mt)
            #pragma unroll
            for (int nt = 0; nt < 4; ++nt) {
                acc[mt][nt] = __builtin_amdgcn_mfma_f32_16x16x32_bf16(bh[nt], ah[mt], acc[mt][nt], 0,0,0);
                acc[mt][nt] = __builtin_amdgcn_mfma_f32_16x16x32_bf16(bl[nt], ah[mt], acc[mt][nt], 0,0,0);
                acc[mt][nt] = __builtin_amdgcn_mfma_f32_16x16x32_bf16(bh[nt], al[mt], acc[mt][nt], 0,0,0);
            }
    }

    unsigned short* __restrict__ dst = (w < 2) ? Ph : Qh;
    const int cbase = (w < 2) ? c0 : c0 - 128;
    #pragma unroll
    for (int mt = 0; mt < 4; ++mt) {
        const int node = n0 + mt*16 + mr;
        #pragma unroll
        for (int nt = 0; nt < 4; ++nt) {
            const int ccb = cbase + nt*16 + qd*4;    // 4 consecutive columns per lane
            float4 bb4 = make_float4(0.f, 0.f, 0.f, 0.f);
            if (w >= 2) bb4 = *(const float4*)&b1[ccb];
            ushort4 o4;
            o4.x = f2h(acc[mt][nt][0] + bb4.x);
            o4.y = f2h(acc[mt][nt][1] + bb4.y);
            o4.z = f2h(acc[mt][nt][2] + bb4.z);
            o4.w = f2h(acc[mt][nt][3] + bb4.w);
            *(ushort4*)&dst[(long)node*HD + ccb] = o4;
        }
    }
}

// ---------------- update GEMM (MFMA swapped-operand, packed-coalesced B) -------------
// ks-loop split into its two static halves (x-half / msum-half): removes the uniform
// in-loop branch and lets the 8 msum float4 loads issue as one batch.
__global__ __launch_bounds__(256) void upd_gemm(
    unsigned short* __restrict__ xhi, unsigned short* __restrict__ xlo,
    const float* __restrict__ msum, const int* __restrict__ degi,
    const unsigned short* __restrict__ wuth, const unsigned short* __restrict__ wutl,
    const float* __restrict__ bias)
{
    const int tid = threadIdx.x;
    const int l = tid & 63, w = tid >> 6;
    const int mr = l & 15, qd = l >> 4;
    const int n0 = blockIdx.x * 64 + w*16;
    const int node = n0 + mr;
    const float inv = 1.f / fmaxf((float)degi[node], 1.f);

    f32x4 acc[8];
    #pragma unroll
    for (int nt = 0; nt < 8; ++nt) acc[nt] = (f32x4){0.f,0.f,0.f,0.f};

    // ---- half 1: ks 0..3, A from xhi/xlo ----
    #pragma unroll 1
    for (int ks = 0; ks < 4; ++ks) {
        const int kof = ks*32 + qd*8;
        const int kb  = ks*4 + qd;
        const bf16x8 ah = *(const bf16x8*)&xhi[node*HD + kof];
        const bf16x8 al = *(const bf16x8*)&xlo[node*HD + kof];
        #pragma unroll
        for (int nt = 0; nt < 8; ++nt) {
            const int c = nt*16 + mr;
            const bf16x8 bh = *(const bf16x8*)&wuth[(kb << 10) + (c << 3)];
            const bf16x8 bl = *(const bf16x8*)&wutl[(kb << 10) + (c << 3)];
            acc[nt] = __builtin_amdgcn_mfma_f32_16x16x32_bf16(bh, ah, acc[nt], 0,0,0);
            acc[nt] = __builtin_amdgcn_mfma_f32_16x16x32_bf16(bl, ah, acc[nt], 0,0,0);
            acc[nt] = __builtin_amdgcn_mfma_f32_16x16x32_bf16(bh, al, acc[nt], 0,0,0);
        }
    }

    // ---- half 2: ks 4..7, A from msum (deg-mean + split2) ----
    #pragma unroll 1
    for (int ks = 4; ks < 8; ++ks) {
        const int kof = ks*32 + qd*8;
        const int kb  = ks*4 + qd;
        const int mk = kof - 128;
        const float4 v0 = *(const float4*)&msum[(long)node*HD + mk];
        const float4 v1 = *(const float4*)&msum[(long)node*HD + mk + 4];
        union { bf16x8 v; unsigned short u[8]; } hh, ll;
        float vv[8] = { v0.x*inv, v0.y*inv, v0.z*inv, v0.w*inv,
                        v1.x*inv, v1.y*inv, v1.z*inv, v1.w*inv };
        #pragma unroll
        for (int i = 0; i < 8; ++i) split2(vv[i], hh.u[i], ll.u[i]);
        const bf16x8 ah = hh.v, al = ll.v;
        #pragma unroll
        for (int nt = 0; nt < 8; ++nt) {
            const int c = nt*16 + mr;
            const bf16x8 bh = *(const bf16x8*)&wuth[(kb << 10) + (c << 3)];
            const bf16x8 bl = *(const bf16x8*)&wutl[(kb << 10) + (c << 3)];
            acc[nt] = __builtin_amdgcn_mfma_f32_16x16x32_bf16(bh, ah, acc[nt], 0,0,0);
            acc[nt] = __builtin_amdgcn_mfma_f32_16x16x32_bf16(bl, ah, acc[nt], 0,0,0);
            acc[nt] = __builtin_amdgcn_mfma_f32_16x16x32_bf16(bh, al, acc[nt], 0,0,0);
        }
    }

    // D^T layout: this lane owns node = n0+mr, columns nt*16 + qd*4 + 0..3
    #pragma unroll
    for (int nt = 0; nt < 8; ++nt) {
        const int cb = nt*16 + qd*4;
        const float4 bb4 = *(const float4*)&bias[cb];
        float o0 = fmaxf(acc[nt][0] + bb4.x, 0.f);
        float o1 = fmaxf(acc[nt][1] + bb4.y, 0.f);
        float o2 = fmaxf(acc[nt][2] + bb4.z, 0.f);
        float o3 = fmaxf(acc[nt][3] + bb4.w, 0.f);
        ushort4 h4, l4;
        split2(o0, h4.x, l4.x); split2(o1, h4.y, l4.y);
        split2(o2, h4.z, l4.z); split2(o3, h4.w, l4.w);
        *(ushort4*)&xhi[(long)node*HD + cb] = h4;
        *(ushort4*)&xlo[(long)node*HD + cb] = l4;
    }
}

// ---------------- fused edge kernel: LDS W2, vmem-free t-loop, global-atomic runs ----
// Round-8 best-known configuration: 256 threads, __launch_bounds__(256,2).
__global__ __launch_bounds__(256, 2) void edge_msg_kernel(
    const unsigned short* __restrict__ Ph, const unsigned short* __restrict__ Qh,
    const uint2* __restrict__ rcD,
    const unsigned short* __restrict__ c1h,   // fp16 [128] dist-col of W1 (layer slice)
    const unsigned short* __restrict__ w2t,   // fp16, swizzled 16B-block layout
    const float* __restrict__ b2,
    float* __restrict__ msum)
{
    __shared__ __align__(16) unsigned short w2s[16384];   // 32 KB
    const int tid = threadIdx.x;

    // ---- stage W2 slice into LDS (global layout == LDS layout, linear copy) ----
    {
        const uint4* __restrict__ src = (const uint4*)w2t;
        uint4* dst = (uint4*)w2s;
        #pragma unroll
        for (int i = 0; i < 8; ++i) dst[tid + i*256] = src[tid + i*256];
    }

    const long e0 = (long)blockIdx.x * 256;
    const int l  = tid & 63;
    const int w  = tid >> 6;
    const int mr = l & 15;
    const int qd = l >> 4;
    const long ebase = e0 + w*64;

    const int aoff = ((mr >> 2) << 4) + (mr & 3);
    int ecol[4], erow[4];
    float edist[4];
    #pragma unroll
    for (int m = 0; m < 4; ++m) {
        const uint2 rd = rcD[ebase + aoff + m*4];
        erow[m] = (int)(rd.x >> 16); ecol[m] = (int)(rd.x & 0xffffu);
        edist[m] = __uint_as_float(rd.y);
    }

    // ---- issue ALL 16 random P gathers first (the long-latency stream) ----
    u16x8 praw[4][4];
    #pragma unroll
    for (int m = 0; m < 4; ++m)
        #pragma unroll
        for (int kk = 0; kk < 4; ++kk)
            praw[m][kk] = *(const u16x8*)&Ph[(long)ecol[m]*HD + kk*32 + qd*8];

    unsigned rcv[16];
    {
        const uint4* rc4 = (const uint4*)&rcD[ebase + qd*16];   // uint4 = 2 edges
        #pragma unroll
        for (int i = 0; i < 8; ++i) {
            const uint4 v = rc4[i];
            rcv[i*2+0] = (v.x >> 16) << 7;
            rcv[i*2+1] = (v.z >> 16) << 7;
        }
    }
    // run-boundary mask, computed ONCE (rows invariant across t-loop)
    unsigned sameMask = 0;
    #pragma unroll
    for (int i = 1; i < 16; ++i) if (rcv[i] == rcv[i-1]) sameMask |= (1u << i);

    // preload ALL per-t biases (kills the in-loop vmem load)
    float b2v[8];
    #pragma unroll
    for (int t = 0; t < 8; ++t) b2v[t] = b2[t*16 + mr];

    // uniform fp16 dist-column (precomputed in wprep — no per-lane cvts)
    f16x8 c8[4];
    #pragma unroll
    for (int kk = 0; kk < 4; ++kk) {
        union { u16x8 raw; f16x8 v; } cu;
        cu.raw = ((const u16x8*)c1h)[kk*4 + qd];
        c8[kk] = cu.v;
    }

    // ---- phase 1: H fragments in packed fp16 (b1 already folded into Q) ----
    const f16x8 z8 = {};
    f16x8 afr[4][4];
    #pragma unroll
    for (int m = 0; m < 4; ++m) {
        union { u16x8 raw; f16x8 v; } qu[4];
        #pragma unroll
        for (int kk = 0; kk < 4; ++kk)
            qu[kk].raw = *(const u16x8*)&Qh[(long)erow[m]*HD + kk*32 + qd*8];
        const _Float16 d16 = (_Float16)edist[m];
        #pragma unroll
        for (int kk = 0; kk < 4; ++kk) {
            union { u16x8 raw; f16x8 v; } pu; pu.raw = praw[m][kk];
            f16x8 s = pu.v + qu[kk].v + d16 * c8[kk];
            afr[m][kk] = __builtin_elementwise_max(s, z8);
        }
    }

    __syncthreads();   // W2 staging complete (overlapped with gathers above)

    // ---- t-loop: ds_read (lgkmcnt) + MFMA + atomics only — no vmem loads ----
    #pragma unroll 1
    for (int t = 0; t < 8; ++t) {
        f16x8 bfr[4];
        #pragma unroll
        for (int kk = 0; kk < 4; ++kk) {
            const int c = kk*4 + qd;
            const int blk = (t*16 + mr)*16 + (c ^ (mr & 7));
            union { u16x8 raw; f16x8 v; } bu;
            bu.raw = *(const u16x8*)&w2s[blk*8];
            bfr[kk] = bu.v;
        }
        const int colg = t*16 + mr;
        const float bb = b2v[t];

        f32x4 acc[4];
        #pragma unroll
        for (int m = 0; m < 4; ++m) acc[m] = (f32x4){0.f, 0.f, 0.f, 0.f};
        #pragma unroll
        for (int kk = 0; kk < 4; ++kk)
            #pragma unroll
            for (int m = 0; m < 4; ++m)
                acc[m] = __builtin_amdgcn_mfma_f32_16x16x32_f16(afr[m][kk], bfr[kk], acc[m], 0, 0, 0);

        // branchless run accumulation; atomic only at run boundaries
        float run = 0.f;
        #pragma unroll
        for (int i = 0; i < 16; ++i) {
            const float v = fmaxf(acc[i>>2][i&3] + bb, 0.f);
            run = (sameMask & (1u << i)) ? run + v : v;
            if (!(sameMask & (2u << i)))        // next row differs (bit16 is 0 -> i==15 flushes)
                atomAdd(&msum[(long)(rcv[i] + colg)], run);
        }
    }
}

// ---------------- ligand-masked per-graph sum: batch-sorted run aggregation --------------
__global__ __launch_bounds__(256) void gsum_kernel(
    const unsigned short* __restrict__ xhi, const unsigned short* __restrict__ xlo,
    const int* __restrict__ batch,
    const int* __restrict__ ntype, float* __restrict__ gsum)
{
    const int tid = threadIdx.x;
    const int cg = tid & 31;          // float4 col group
    const int ns = tid >> 5;          // node strip 0..7
    const int n0 = blockIdx.x * 512 + ns * 64;

    int bprev = -1;
    float4 run = make_float4(0.f, 0.f, 0.f, 0.f);
    for (int i = 0; i < 64; ++i) {
        const int n = n0 + i;
        if (ntype[n] != 1) continue;
        const int b = batch[n];
        const ushort4 h  = *(const ushort4*)&xhi[(long)n*HD + cg*4];
        const ushort4 lo = *(const ushort4*)&xlo[(long)n*HD + cg*4];
        float4 v;
        v.x = bf2f(h.x) + bf2f(lo.x);
        v.y = bf2f(h.y) + bf2f(lo.y);
        v.z = bf2f(h.z) + bf2f(lo.z);
        v.w = bf2f(h.w) + bf2f(lo.w);
        if (b != bprev) {
            if (bprev >= 0) {
                float* dst = &gsum[bprev*HD + cg*4];
                atomAdd(dst+0, run.x); atomAdd(dst+1, run.y);
                atomAdd(dst+2, run.z); atomAdd(dst+3, run.w);
            }
            bprev = b; run = v;
        } else {
            run.x += v.x; run.y += v.y; run.z += v.z; run.w += v.w;
        }
    }
    if (bprev >= 0) {
        float* dst = &gsum[bprev*HD + cg*4];
        atomAdd(dst+0, run.x); atomAdd(dst+1, run.y);
        atomAdd(dst+2, run.z); atomAdd(dst+3, run.w);
    }
}

// ---------------- readout ----------------
__global__ __launch_bounds__(128) void readout_kernel(
    const float* __restrict__ gsum, const float* __restrict__ lcnt,
    const float* __restrict__ w1, const float* __restrict__ b1,
    const float* __restrict__ w2, const float* __restrict__ b2,
    float* __restrict__ out)
{
    __shared__ float gs[HD];
    __shared__ float red[2];
    const int b = blockIdx.x, j = threadIdx.x;
    gs[j] = gsum[b*HD + j] / fmaxf(lcnt[b], 1.f);
    __syncthreads();
    float acc = b1[j];
    for (int k = 0; k < HD; ++k) acc += gs[k]*w1[k*HD + j];
    float hg = fmaxf(acc, 0.f) * w2[j];
    #pragma unroll
    for (int off = 32; off > 0; off >>= 1) hg += __shfl_down(hg, off, 64);
    if ((j & 63) == 0) red[j >> 6] = hg;
    __syncthreads();
    if (j == 0) out[b] = red[0] + red[1] + b2[0];
}

extern "C" void kernel_launch(void* const* d_in, const int* in_sizes, int n_in,
                              void* d_out, int out_size, void* d_ws, size_t ws_size,
                              hipStream_t stream)
{
    const float* pos   = (const float*)d_in[0];
    const int*   z     = (const int*)d_in[1];
    const int*   batch = (const int*)d_in[2];
    const int*   eidx  = (const int*)d_in[3];
    const int*   ntype = (const int*)d_in[4];
    const float* emb   = (const float*)d_in[5];
    const float* lin_w = (const float*)d_in[6];
    const float* lin_b = (const float*)d_in[7];
    const float* mw1   = (const float*)d_in[8];
    const float* mb1   = (const float*)d_in[9];
    const float* mw2   = (const float*)d_in[10];
    const float* mb2   = (const float*)d_in[11];
    const float* uw    = (const float*)d_in[12];
    const float* ub    = (const float*)d_in[13];
    const float* rw1   = (const float*)d_in[14];
    const float* rb1   = (const float*)d_in[15];
    const float* rw2   = (const float*)d_in[16];
    const float* rb2   = (const float*)d_in[17];

    const int* row = eidx;
    const int* col = eidx + NE;

    float* ws     = (float*)d_ws;
    float* csum   = ws + O_CSUM;
    float* ccnt   = ws + O_CCNT;
    float* lcnt   = ws + O_LCNT;
    float* gsum   = ws + O_GSUM;
    int*   degi   = (int*)(ws + O_DEGI);
    float* posrel = ws + O_POSREL;
    unsigned short* xhi = (unsigned short*)(ws + O_XHI);
    unsigned short* xlo = (unsigned short*)(ws + O_XLO);
    unsigned short* Ph  = (unsigned short*)(ws + O_P);
    uint2* rcD    = (uint2*)(ws + O_RCD);
    unsigned short* Qh  = (unsigned short*)(ws + O_Q);
    unsigned short* c1h = (unsigned short*)(ws + O_C1H);
    float* EW     = ws + O_EW;
    float* msum   = ws + O_MSUM;
    unsigned short* w2t  = (unsigned short*)(ws + O_W2T);
    unsigned short* w1th = (unsigned short*)(ws + O_W1TH);
    unsigned short* w1tl = (unsigned short*)(ws + O_W1TL);
    unsigned short* wuth = (unsigned short*)(ws + O_WUTH);
    unsigned short* wutl = (unsigned short*)(ws + O_WUTL);
    int* chunkSum = (int*)(ws + O_CHK);
    int* rowStart = (int*)xhi;           // alias xhi head pre-lin_in
    int* cnt      = (int*)xhi + NN;

    (void)hipMemsetAsync(ws, 0, (size_t)(O_DEGI + NN) * sizeof(float), stream);
    (void)hipMemsetAsync(cnt, 0, (size_t)NN * sizeof(int), stream);

    stats_kernel  <<<NN/256, 256, 0, stream>>>(pos, batch, ntype, csum, ccnt, lcnt);
    deg_kernel    <<<NE/256, 256, 0, stream>>>(row, degi);
    posrel_kernel <<<NN/256, 256, 0, stream>>>(pos, batch, csum, ccnt, posrel);
    scanA_kernel  <<<256, 256, 0, stream>>>(degi, chunkSum);
    scanB_kernel  <<<1, 256, 0, stream>>>(chunkSum);
    scanC_kernel  <<<256, 256, 0, stream>>>(degi, chunkSum, rowStart);
    scatter_kernel<<<NE/256, 256, 0, stream>>>(row, col, rowStart, cnt, rcD, posrel);
    wprep_kernel  <<<384, 256, 0, stream>>>(mw1, uw, mw2, lin_w, lin_b, emb,
                                            w1th, w1tl, wuth, wutl, w2t, c1h, EW);

    lin_in_kernel<<<NN/16, 256, 0, stream>>>(EW, posrel, z, lin_w, xhi, xlo);

    for (int l = 0; l < NL; ++l) {
        pq_gemm<<<NN/64, 256, 0, stream>>>(xhi, xlo,
                                           w1th + (size_t)l*32768, w1tl + (size_t)l*32768,
                                           Ph, Qh, msum, mb1 + (size_t)l*HD);
        edge_msg_kernel<<<NE/256, 256, 0, stream>>>(Ph, Qh, rcD,
                                                    c1h + (size_t)l*HD,
                                                    w2t + (size_t)l*16384, mb2 + l*HD, msum);
        upd_gemm<<<NN/64, 256, 0, stream>>>(xhi, xlo, msum, degi,
                                            wuth + (size_t)l*32768, wutl + (size_t)l*32768,
                                            ub + l*HD);
    }

    gsum_kernel   <<<NN/512, 256, 0, stream>>>(xhi, xlo, batch, ntype, gsum);
    readout_kernel<<<NB, 128, 0, stream>>>(gsum, lcnt, rw1, rb1, rw2, rb2, (float*)d_out);
}